// Round 13
// baseline (101.984 us; speedup 1.0000x reference)
//
#include <hip/hip_runtime.h>

typedef unsigned short u16;
typedef unsigned int   u32;
typedef __bf16 bf16x8 __attribute__((ext_vector_type(8)));
typedef float  f32x4  __attribute__((ext_vector_type(4)));
typedef float  f32x16 __attribute__((ext_vector_type(16)));
typedef u16    u16x4  __attribute__((ext_vector_type(4)));
typedef u32    u32x4  __attribute__((ext_vector_type(4)));

#define HH   16
#define DHH  64
#define SEQL 2048
#define NB   2
#define BHN  (NB * HH)   // 32
#define SCLF 0.1803368801111204f   // 0.125 * log2(e)
#define KVB  128                    // keys staged per iteration (64 A + 64 B)
#define NT   16                     // iterations; stream covers 16*64 = 1024

static __device__ __forceinline__ u16 f2bf(float f) {
    return __builtin_bit_cast(u16, (__bf16)f);
}
static __device__ __forceinline__ u32 pack2(float a, float b) {
    return (u32)f2bf(a) | ((u32)f2bf(b) << 16);
}
// v_permlane32_swap_b32: dst.lanes[32:63] <-> src.lanes[0:31]
static __device__ __forceinline__ void plswap(u32 &a, u32 &b) {
    asm volatile("v_permlane32_swap_b32 %0, %1" : "+v"(a), "+v"(b));
}

// direct global->LDS DMA, 16B per lane; LDS dest = wave-uniform base + lane*16
static __device__ __forceinline__ void gload_lds16(const void* g, void* l) {
    __builtin_amdgcn_global_load_lds(
        (const __attribute__((address_space(1))) unsigned int*)g,
        (__attribute__((address_space(3))) unsigned int*)l, 16, 0, 0);
}

// ---------------------------------------------------------------------------
// Kernel 0: one-time W f32 -> bf16 pre-cast.  Wb layout: [m][h][e][d] bf16.
// Wq is pre-scaled by SCLF so QK^T lands directly in the exp2 domain.
// ---------------------------------------------------------------------------
__global__ __launch_bounds__(256) void wconv_kernel(
    const float* __restrict__ Wq, const float* __restrict__ Wk,
    const float* __restrict__ Wv, u16* __restrict__ Wb)
{
    const int m = blockIdx.y;
    const float* W = (m == 0) ? Wq : (m == 1) ? Wk : Wv;
    const float s = (m == 0) ? SCLF : 1.0f;
    const int i = (blockIdx.x * 256 + threadIdx.x) * 4;   // 65536 f32 per matrix
    float4 v = *reinterpret_cast<const float4*>(W + i);
    u16x4 o = { f2bf(v.x * s), f2bf(v.y * s), f2bf(v.z * s), f2bf(v.w * s) };
    *reinterpret_cast<u16x4*>(Wb + (size_t)m * 65536 + i) = o;
}

// ---------------------------------------------------------------------------
// Kernel 1: per-head QKV projection.  x[B,S,D] f32 -> Q,K bf16 [bh][S][64],
// V^T bf16 [bh][64][S].  One block = 64 rows x 1 head, 4 waves x 16 rows.
// All global stores coalesced 16B via the LDS repack tile.
// ---------------------------------------------------------------------------
__global__ __launch_bounds__(256) void qkv_kernel(
    const float* __restrict__ x, const u16* __restrict__ Wb,
    const float* __restrict__ bq, const float* __restrict__ bk,
    const float* __restrict__ bv,
    u16* __restrict__ Qws, u16* __restrict__ Kws, u16* __restrict__ Vtws)
{
    const int h   = blockIdx.y;
    const int r0  = blockIdx.x * 64;          // row in [0, B*S)
    const int tid = threadIdx.x;
    const int w   = tid >> 6;
    const int l   = tid & 63;
    const int c   = l & 15;
    const int g   = l >> 4;

    __shared__ u16 vt[64 * 72];               // repack tile (reused Q,K,V)

    bf16x8 xa[2];
    {
        const float* xp = x + (size_t)(r0 + w * 16 + c) * 1024 + h * 64 + g * 8;
        #pragma unroll
        for (int kh = 0; kh < 2; ++kh) {
            float4 lo = *reinterpret_cast<const float4*>(xp + kh * 32);
            float4 hi = *reinterpret_cast<const float4*>(xp + kh * 32 + 4);
            bf16x8 f;
            f[0]=(__bf16)lo.x; f[1]=(__bf16)lo.y; f[2]=(__bf16)lo.z; f[3]=(__bf16)lo.w;
            f[4]=(__bf16)hi.x; f[5]=(__bf16)hi.y; f[6]=(__bf16)hi.z; f[7]=(__bf16)hi.w;
            xa[kh] = f;
        }
    }

    const int b      = r0 >> 11;              // / SEQL
    const int s_base = r0 & (SEQL - 1);
    const int bh     = b * HH + h;

    const float* bs[3] = {bq + h * 64, bk + h * 64, bv + h * 64};

    #pragma unroll
    for (int m = 0; m < 3; ++m) {
        const u16*   W    = Wb + (size_t)m * 65536 + h * 4096;
        const float* bias = bs[m];
        const float  bscl = (m == 0) ? SCLF : 1.0f;
        f32x4 acc[4];
        #pragma unroll
        for (int ct = 0; ct < 4; ++ct) {
            acc[ct][0] = 0.f; acc[ct][1] = 0.f; acc[ct][2] = 0.f; acc[ct][3] = 0.f;
        }
        #pragma unroll
        for (int kh = 0; kh < 2; ++kh) {
            #pragma unroll
            for (int ct = 0; ct < 4; ++ct) {
                bf16x8 wf = *reinterpret_cast<const bf16x8*>(
                    W + (ct * 16 + c) * 64 + kh * 32 + g * 8);
                acc[ct] = __builtin_amdgcn_mfma_f32_16x16x32_bf16(xa[kh], wf, acc[ct], 0, 0, 0);
            }
        }
        // C layout: col(e) = ct*16+c, row(s within 16) = g*4 + r
        if (m < 2) {
            if (m == 1) __syncthreads();
            #pragma unroll
            for (int ct = 0; ct < 4; ++ct) {
                float bb = bias[ct * 16 + c] * bscl;
                #pragma unroll
                for (int r = 0; r < 4; ++r)
                    vt[(w * 16 + g * 4 + r) * 72 + ct * 16 + c] = f2bf(acc[ct][r] + bb);
            }
            __syncthreads();
            {
                const int d  = tid >> 2;
                const int s0 = (tid & 3) * 16;
                u16* outp = (m == 0 ? Qws : Kws) +
                            ((size_t)bh * SEQL + s_base + d) * 64 + s0;
                uint4 v0 = *reinterpret_cast<const uint4*>(&vt[d * 72 + s0]);
                uint4 v1 = *reinterpret_cast<const uint4*>(&vt[d * 72 + s0 + 8]);
                *reinterpret_cast<uint4*>(outp)     = v0;
                *reinterpret_cast<uint4*>(outp + 8) = v1;
            }
        } else {
            __syncthreads();
            #pragma unroll
            for (int ct = 0; ct < 4; ++ct) {
                float bb = bias[ct * 16 + c];
                u16x4 pb;
                #pragma unroll
                for (int r = 0; r < 4; ++r)
                    pb[r] = f2bf(acc[ct][r] + bb);
                *reinterpret_cast<u16x4*>(&vt[(ct * 16 + c) * 72 + w * 16 + g * 4]) = pb;
            }
            __syncthreads();
            {
                const int d  = tid >> 2;
                const int s0 = (tid & 3) * 16;
                u16* vp = Vtws + ((size_t)bh * 64 + d) * SEQL + s_base + s0;
                uint4 v0 = *reinterpret_cast<const uint4*>(&vt[d * 72 + s0]);
                uint4 v1 = *reinterpret_cast<const uint4*>(&vt[d * 72 + s0 + 8]);
                *reinterpret_cast<uint4*>(vp)     = v0;
                *reinterpret_cast<uint4*>(vp + 8) = v1;
            }
        }
    }
}

// ---------------------------------------------------------------------------
// Kernel 2: flash attention — R13: TWO independent key-streams per wave
// (in-wave split-K).  Stream A = keys [0,1024), stream B = [1024,2048),
// separate (m,l,acc), interleaved per iteration so QK_B overlaps softmax_A
// and PV_A overlaps softmax_B (independent dependency chains).  Exact
// in-register merge at the end.  32x32 MFMA + permlane in-register P (R11);
// K/V double-buffered via swizzled global_load_lds; one barrier per iter.
// ---------------------------------------------------------------------------
__global__ __launch_bounds__(256, 2) void attn_kernel(
    const u16* __restrict__ Qws, const u16* __restrict__ Kws,
    const u16* __restrict__ Vtws, float* __restrict__ out)
{
    // XCD-chunk swizzle: 512 blocks -> 64 consecutive logical blocks per XCD.
    const int p     = blockIdx.x;
    const int lid   = (p & 7) * 64 + (p >> 3);
    const int qtile = lid & 15;
    const int bh    = lid >> 4;
    const int b     = bh >> 4;
    const int h     = bh & 15;

    const int tid = threadIdx.x;
    const int w   = tid >> 6;
    const int l   = tid & 63;
    const int lq  = l & 31;                   // lane's q-row
    const int hi  = l >> 5;                   // lane half
    const int q0  = qtile * 128 + w * 32;

    __shared__ u16 k_lds[2][KVB * 64];        // rows 0-63: A keys, 64-127: B
    __shared__ u16 v_lds[2][64 * KVB];        // slots 0-7: A keys, 8-15: B

    const u16* Kb = Kws  + (size_t)bh * SEQL * 64;
    const u16* Vb = Vtws + (size_t)bh * 64 * SEQL;

    // stage 64 A-keys + 64 B-keys into buffer bb.
    // K: 128 rows x 128B (8 slots of 16B, slot ^= row&7); waves 0,1 -> A rows,
    //    waves 2,3 -> B rows.  V: 64 d-rows x 256B (16 slots; slot ^= row&15),
    //    slots 0-7 map to A keys, 8-15 to B keys (per-lane select).
    #define STAGE(bb, k0A, k0B)                                               \
    {   const int rs8 = l >> 3, c8 = l & 7;                                   \
        const int kbw = (w < 2) ? (k0A) : ((k0B) - 64);                       \
        _Pragma("unroll")                                                     \
        for (int a = 0; a < 4; ++a) {                                         \
            const int rbase = w * 32 + a * 8;                                 \
            gload_lds16(Kb + (size_t)(kbw + rbase + rs8) * 64 + (c8 ^ rs8) * 8, \
                        &k_lds[bb][rbase * 64]);                              \
        }                                                                     \
        const int rs16 = l >> 4, c16 = l & 15;                                \
        _Pragma("unroll")                                                     \
        for (int a = 0; a < 4; ++a) {                                         \
            const int rbase = w * 16 + a * 4;                                 \
            const int sxv   = c16 ^ ((a * 4 + rs16) & 15);                    \
            const int kk    = (sxv < 8) ? ((k0A) + sxv * 8)                   \
                                        : ((k0B) + (sxv - 8) * 8);            \
            gload_lds16(Vb + (size_t)(rbase + rs16) * SEQL + kk,              \
                        &v_lds[bb][rbase * KVB]);                             \
        }                                                                     \
    }

    // Q fragments (B of S^T): Q[q0+lq][s*16 + hi*8 ..+8]
    bf16x8 qf[4];
    #pragma unroll
    for (int s = 0; s < 4; ++s)
        qf[s] = *reinterpret_cast<const bf16x8*>(
            Qws + ((size_t)bh * SEQL + q0 + lq) * 64 + s * 16 + hi * 8);

    f32x16 zero16;
    #pragma unroll
    for (int j = 0; j < 16; ++j) zero16[j] = 0.f;

    f32x16 accA[2], accB[2];                  // O^T accum per stream
    accA[0] = zero16; accA[1] = zero16;
    accB[0] = zero16; accB[1] = zero16;
    float mrowA = -1e30f, lrowA = 0.f;
    float mrowB = -1e30f, lrowB = 0.f;

    // K read slots (bytes within 128B row); row&7 == lq&7 for all sub-tiles
    int koff[4];
    #pragma unroll
    for (int s = 0; s < 4; ++s) koff[s] = ((s * 2 + hi) ^ (lq & 7)) * 16;

    // softmax + P-pack for one stream (updates m,l,acc; fills pf)
    auto smax = [&](const f32x16& st0, const f32x16& st1,
                    float& mrow, float& lrow, f32x16 (&acc)[2],
                    bf16x8 (&pf)[4]) {
        float t0 = fmaxf(fmaxf(st0[0], st0[1]),  fmaxf(st0[2], st0[3]));
        float t1 = fmaxf(fmaxf(st0[4], st0[5]),  fmaxf(st0[6], st0[7]));
        float t2 = fmaxf(fmaxf(st0[8], st0[9]),  fmaxf(st0[10], st0[11]));
        float t3 = fmaxf(fmaxf(st0[12], st0[13]), fmaxf(st0[14], st0[15]));
        float t4 = fmaxf(fmaxf(st1[0], st1[1]),  fmaxf(st1[2], st1[3]));
        float t5 = fmaxf(fmaxf(st1[4], st1[5]),  fmaxf(st1[6], st1[7]));
        float t6 = fmaxf(fmaxf(st1[8], st1[9]),  fmaxf(st1[10], st1[11]));
        float t7 = fmaxf(fmaxf(st1[12], st1[13]), fmaxf(st1[14], st1[15]));
        float mx = fmaxf(fmaxf(fmaxf(t0, t1), fmaxf(t2, t3)),
                         fmaxf(fmaxf(t4, t5), fmaxf(t6, t7)));
        mx = fmaxf(mx, __shfl_xor(mx, 32, 64));

        if (!__all(mx <= mrow + 8.f)) {       // T13 defer-rescale
            const float mn    = fmaxf(mrow, mx);
            const float alpha = __builtin_amdgcn_exp2f(mrow - mn);
            mrow = mn;
            lrow *= alpha;
            #pragma unroll
            for (int j = 0; j < 16; ++j) { acc[0][j] *= alpha; acc[1][j] *= alpha; }
        }

        float rs0 = 0.f, rs1 = 0.f;
        u32 wd[16];
        {
            float pp[16];
            #pragma unroll
            for (int r = 0; r < 16; ++r) {
                pp[r] = __builtin_amdgcn_exp2f(st0[r] - mrow);
                if (r & 1) rs1 += pp[r]; else rs0 += pp[r];
            }
            #pragma unroll
            for (int j = 0; j < 8; ++j) wd[j] = pack2(pp[2 * j], pp[2 * j + 1]);
        }
        {
            float pp[16];
            #pragma unroll
            for (int r = 0; r < 16; ++r) {
                pp[r] = __builtin_amdgcn_exp2f(st1[r] - mrow);
                if (r & 1) rs1 += pp[r]; else rs0 += pp[r];
            }
            #pragma unroll
            for (int j = 0; j < 8; ++j) wd[8 + j] = pack2(pp[2 * j], pp[2 * j + 1]);
        }
        lrow += rs0 + rs1;

        plswap(wd[0],  wd[2]);  plswap(wd[1],  wd[3]);
        plswap(wd[4],  wd[6]);  plswap(wd[5],  wd[7]);
        plswap(wd[8],  wd[10]); plswap(wd[9],  wd[11]);
        plswap(wd[12], wd[14]); plswap(wd[13], wd[15]);

        #pragma unroll
        for (int s = 0; s < 4; ++s) {
            u32x4 tmp = { wd[s * 4 + 0], wd[s * 4 + 1], wd[s * 4 + 2], wd[s * 4 + 3] };
            pf[s] = __builtin_bit_cast(bf16x8, tmp);
        }
    };

    STAGE(0, 0, 1024);
    __syncthreads();

    for (int t = 0; t < NT; ++t) {
        const int cur = t & 1;
        if (t + 1 < NT) STAGE(cur ^ 1, (t + 1) * 64, 1024 + (t + 1) * 64);

        const char* kb = reinterpret_cast<const char*>(&k_lds[cur][0]);
        const char* vb = reinterpret_cast<const char*>(&v_lds[cur][0]);

        // ---- QK for BOTH streams (16 MFMAs queued back-to-back)
        f32x16 sA0, sA1, sB0, sB1;
        __builtin_amdgcn_s_setprio(1);
        {
            bf16x8 k0[4], k1[4];
            #pragma unroll
            for (int s = 0; s < 4; ++s) {
                k0[s] = *reinterpret_cast<const bf16x8*>(kb + lq * 128 + koff[s]);
                k1[s] = *reinterpret_cast<const bf16x8*>(kb + (32 + lq) * 128 + koff[s]);
            }
            sA0 = __builtin_amdgcn_mfma_f32_32x32x16_bf16(k0[0], qf[0], zero16, 0, 0, 0);
            sA1 = __builtin_amdgcn_mfma_f32_32x32x16_bf16(k1[0], qf[0], zero16, 0, 0, 0);
            #pragma unroll
            for (int s = 1; s < 4; ++s) {
                sA0 = __builtin_amdgcn_mfma_f32_32x32x16_bf16(k0[s], qf[s], sA0, 0, 0, 0);
                sA1 = __builtin_amdgcn_mfma_f32_32x32x16_bf16(k1[s], qf[s], sA1, 0, 0, 0);
            }
        }
        {
            bf16x8 k0[4], k1[4];
            #pragma unroll
            for (int s = 0; s < 4; ++s) {
                k0[s] = *reinterpret_cast<const bf16x8*>(kb + (64 + lq) * 128 + koff[s]);
                k1[s] = *reinterpret_cast<const bf16x8*>(kb + (96 + lq) * 128 + koff[s]);
            }
            sB0 = __builtin_amdgcn_mfma_f32_32x32x16_bf16(k0[0], qf[0], zero16, 0, 0, 0);
            sB1 = __builtin_amdgcn_mfma_f32_32x32x16_bf16(k1[0], qf[0], zero16, 0, 0, 0);
            #pragma unroll
            for (int s = 1; s < 4; ++s) {
                sB0 = __builtin_amdgcn_mfma_f32_32x32x16_bf16(k0[s], qf[s], sB0, 0, 0, 0);
                sB1 = __builtin_amdgcn_mfma_f32_32x32x16_bf16(k1[s], qf[s], sB1, 0, 0, 0);
            }
        }
        __builtin_amdgcn_s_setprio(0);

        // ---- V fragments for both streams (LDS reads issue early)
        bf16x8 vfA[2][4], vfB[2][4];
        #pragma unroll
        for (int dt = 0; dt < 2; ++dt)
            #pragma unroll
            for (int s = 0; s < 4; ++s) {
                const int sa = (s * 2 + hi) ^ (lq & 15);
                const int sb = (8 + s * 2 + hi) ^ (lq & 15);
                vfA[dt][s] = *reinterpret_cast<const bf16x8*>(
                    vb + (dt * 32 + lq) * 256 + sa * 16);
                vfB[dt][s] = *reinterpret_cast<const bf16x8*>(
                    vb + (dt * 32 + lq) * 256 + sb * 16);
            }

        // ---- softmax_A (VALU) — overlaps QK_B retiring on the matrix pipe
        bf16x8 pfA[4];
        smax(sA0, sA1, mrowA, lrowA, accA, pfA);

        // ---- PV_A (matrix pipe) — overlaps softmax_B below
        __builtin_amdgcn_s_setprio(1);
        #pragma unroll
        for (int s = 0; s < 4; ++s) {
            accA[0] = __builtin_amdgcn_mfma_f32_32x32x16_bf16(vfA[0][s], pfA[s], accA[0], 0, 0, 0);
            accA[1] = __builtin_amdgcn_mfma_f32_32x32x16_bf16(vfA[1][s], pfA[s], accA[1], 0, 0, 0);
        }
        __builtin_amdgcn_s_setprio(0);

        // ---- softmax_B (VALU)
        bf16x8 pfB[4];
        smax(sB0, sB1, mrowB, lrowB, accB, pfB);

        // ---- PV_B (matrix pipe)
        __builtin_amdgcn_s_setprio(1);
        #pragma unroll
        for (int s = 0; s < 4; ++s) {
            accB[0] = __builtin_amdgcn_mfma_f32_32x32x16_bf16(vfB[0][s], pfB[s], accB[0], 0, 0, 0);
            accB[1] = __builtin_amdgcn_mfma_f32_32x32x16_bf16(vfB[1][s], pfB[s], accB[1], 0, 0, 0);
        }
        __builtin_amdgcn_s_setprio(0);

        // one barrier per iteration: drains vmcnt (stage of t+1), protects buf
        __syncthreads();
    }

    // ---- exact merge of the two streams, normalize, store
    const float mn = fmaxf(mrowA, mrowB);
    const float aA = __builtin_amdgcn_exp2f(mrowA - mn);
    const float aB = __builtin_amdgcn_exp2f(mrowB - mn);
    const float lA = lrowA + __shfl_xor(lrowA, 32, 64);
    const float lB = lrowB + __shfl_xor(lrowB, 32, 64);
    const float inv = 1.f / (lA * aA + lB * aB);

    // O^T[d][q]: d = dt*32 + rg*8 + hi*4 + (r&3), q = q0+lq
    float* op = out + ((size_t)b * SEQL + q0 + lq) * 1024 + h * 64 + hi * 4;
    #pragma unroll
    for (int dt = 0; dt < 2; ++dt)
        #pragma unroll
        for (int rg = 0; rg < 4; ++rg) {
            float4 o;
            #pragma unroll
            for (int j = 0; j < 4; ++j)
                ((float*)&o)[j] = (accA[dt][rg * 4 + j] * aA +
                                   accB[dt][rg * 4 + j] * aB) * inv;
            *reinterpret_cast<float4*>(op + dt * 32 + rg * 8) = o;
        }
}

extern "C" void kernel_launch(void* const* d_in, const int* in_sizes, int n_in,
                              void* d_out, int out_size, void* d_ws, size_t ws_size,
                              hipStream_t stream) {
    const float* x  = (const float*)d_in[0];
    const float* Wq = (const float*)d_in[1];
    const float* bq = (const float*)d_in[2];
    const float* Wk = (const float*)d_in[3];
    const float* bk = (const float*)d_in[4];
    const float* Wv = (const float*)d_in[5];
    const float* bv = (const float*)d_in[6];
    float* out = (float*)d_out;

    const size_t per = (size_t)BHN * SEQL * 64;   // 4Mi elems per matrix
    u16* Qws = (u16*)d_ws;
    u16* Kws = Qws + per;
    u16* Vt  = Kws + per;
    u16* Wb  = Vt  + per;                         // 3*65536 bf16 = 384 KB

    wconv_kernel<<<dim3(64, 3), 256, 0, stream>>>(Wq, Wk, Wv, Wb);
    qkv_kernel<<<dim3(64, 16), 256, 0, stream>>>(x, Wb, bq, bk, bv, Qws, Kws, Vt);
    attn_kernel<<<dim3(512), 256, 0, stream>>>(Qws, Kws, Vt, out);
}

// Round 14
// 84.956 us; speedup vs baseline: 1.2004x; 1.2004x over previous
//
#include <hip/hip_runtime.h>

typedef unsigned short u16;
typedef unsigned int   u32;
typedef __bf16 bf16x8 __attribute__((ext_vector_type(8)));
typedef float  f32x4  __attribute__((ext_vector_type(4)));
typedef float  f32x16 __attribute__((ext_vector_type(16)));
typedef u16    u16x4  __attribute__((ext_vector_type(4)));
typedef u32    u32x4  __attribute__((ext_vector_type(4)));

#define HH   16
#define DHH  64
#define SEQL 2048
#define NB   2
#define BHN  (NB * HH)   // 32
#define SCLF 0.1803368801111204f   // 0.125 * log2(e)

static __device__ __forceinline__ u16 f2bf(float f) {
    return __builtin_bit_cast(u16, (__bf16)f);
}
static __device__ __forceinline__ u32 pack2(float a, float b) {
    return (u32)f2bf(a) | ((u32)f2bf(b) << 16);
}
// v_permlane32_swap_b32: dst.lanes[32:63] <-> src.lanes[0:31]
static __device__ __forceinline__ void plswap(u32 &a, u32 &b) {
    asm volatile("v_permlane32_swap_b32 %0, %1" : "+v"(a), "+v"(b));
}

// direct global->LDS DMA, 16B per lane; LDS dest = wave-uniform base + lane*16
static __device__ __forceinline__ void gload_lds16(const void* g, void* l) {
    __builtin_amdgcn_global_load_lds(
        (const __attribute__((address_space(1))) unsigned int*)g,
        (__attribute__((address_space(3))) unsigned int*)l, 16, 0, 0);
}

// ---------------------------------------------------------------------------
// Kernel 0: one-time W f32 -> bf16 pre-cast.  Wb layout: [m][h][e][d] bf16.
// Wq is pre-scaled by SCLF so QK^T lands directly in the exp2 domain.
// ---------------------------------------------------------------------------
__global__ __launch_bounds__(256) void wconv_kernel(
    const float* __restrict__ Wq, const float* __restrict__ Wk,
    const float* __restrict__ Wv, u16* __restrict__ Wb)
{
    const int m = blockIdx.y;
    const float* W = (m == 0) ? Wq : (m == 1) ? Wk : Wv;
    const float s = (m == 0) ? SCLF : 1.0f;
    const int i = (blockIdx.x * 256 + threadIdx.x) * 4;   // 65536 f32 per matrix
    float4 v = *reinterpret_cast<const float4*>(W + i);
    u16x4 o = { f2bf(v.x * s), f2bf(v.y * s), f2bf(v.z * s), f2bf(v.w * s) };
    *reinterpret_cast<u16x4*>(Wb + (size_t)m * 65536 + i) = o;
}

// ---------------------------------------------------------------------------
// Kernel 1: per-head QKV projection.  x[B,S,D] f32 -> Q,K bf16 [bh][S][64],
// V^T bf16 [bh][64][S].  One block = 64 rows x 1 head, 4 waves x 16 rows.
// R14: all 24 MFMAs computed up front (3 matrices interleaved, W loads
// batched), separate LDS tiles for Q/K/V, ONE barrier (was 6), then 6
// coalesced 16B stores per thread.
// ---------------------------------------------------------------------------
__global__ __launch_bounds__(256) void qkv_kernel(
    const float* __restrict__ x, const u16* __restrict__ Wb,
    const float* __restrict__ bq, const float* __restrict__ bk,
    const float* __restrict__ bv,
    u16* __restrict__ Qws, u16* __restrict__ Kws, u16* __restrict__ Vtws)
{
    const int h   = blockIdx.y;
    const int r0  = blockIdx.x * 64;          // row in [0, B*S)
    const int tid = threadIdx.x;
    const int w   = tid >> 6;
    const int l   = tid & 63;
    const int c   = l & 15;
    const int g   = l >> 4;

    __shared__ u16 qt[64 * 72];               // Q tile [s][e]
    __shared__ u16 kt[64 * 72];               // K tile [s][e]
    __shared__ u16 vt[64 * 72];               // V tile transposed [e][s]

    bf16x8 xa[2];
    {
        const float* xp = x + (size_t)(r0 + w * 16 + c) * 1024 + h * 64 + g * 8;
        #pragma unroll
        for (int kh = 0; kh < 2; ++kh) {
            float4 lo = *reinterpret_cast<const float4*>(xp + kh * 32);
            float4 hi = *reinterpret_cast<const float4*>(xp + kh * 32 + 4);
            bf16x8 f;
            f[0]=(__bf16)lo.x; f[1]=(__bf16)lo.y; f[2]=(__bf16)lo.z; f[3]=(__bf16)lo.w;
            f[4]=(__bf16)hi.x; f[5]=(__bf16)hi.y; f[6]=(__bf16)hi.z; f[7]=(__bf16)hi.w;
            xa[kh] = f;
        }
    }

    const int b      = r0 >> 11;              // / SEQL
    const int s_base = r0 & (SEQL - 1);
    const int bh     = b * HH + h;

    // ---- all 24 MFMAs (3 matrices x 2 k-halves x 4 col-tiles), batched
    f32x4 acc[3][4];
    #pragma unroll
    for (int m = 0; m < 3; ++m)
        #pragma unroll
        for (int ct = 0; ct < 4; ++ct) {
            acc[m][ct][0] = 0.f; acc[m][ct][1] = 0.f;
            acc[m][ct][2] = 0.f; acc[m][ct][3] = 0.f;
        }
    #pragma unroll
    for (int kh = 0; kh < 2; ++kh)
        #pragma unroll
        for (int m = 0; m < 3; ++m) {
            const u16* W = Wb + (size_t)m * 65536 + h * 4096;
            #pragma unroll
            for (int ct = 0; ct < 4; ++ct) {
                bf16x8 wf = *reinterpret_cast<const bf16x8*>(
                    W + (ct * 16 + c) * 64 + kh * 32 + g * 8);
                acc[m][ct] = __builtin_amdgcn_mfma_f32_16x16x32_bf16(xa[kh], wf, acc[m][ct], 0, 0, 0);
            }
        }

    // ---- repack all three into LDS; C layout: col(e)=ct*16+c, row=g*4+r
    #pragma unroll
    for (int ct = 0; ct < 4; ++ct) {
        const float bbq = bq[h * 64 + ct * 16 + c] * SCLF;
        const float bbk = bk[h * 64 + ct * 16 + c];
        const float bbv = bv[h * 64 + ct * 16 + c];
        u16x4 pv;
        #pragma unroll
        for (int r = 0; r < 4; ++r) {
            const int srow = w * 16 + g * 4 + r;
            qt[srow * 72 + ct * 16 + c] = f2bf(acc[0][ct][r] + bbq);
            kt[srow * 72 + ct * 16 + c] = f2bf(acc[1][ct][r] + bbk);
            pv[r] = f2bf(acc[2][ct][r] + bbv);
        }
        // V transposed [e][s]: rows r contiguous -> b64 write
        *reinterpret_cast<u16x4*>(&vt[(ct * 16 + c) * 72 + w * 16 + g * 4]) = pv;
    }
    __syncthreads();

    // ---- coalesced stores: 6 x 16B per thread
    {
        const int d  = tid >> 2;
        const int s0 = (tid & 3) * 16;
        u16* qp = Qws + ((size_t)bh * SEQL + s_base + d) * 64 + s0;
        *reinterpret_cast<uint4*>(qp)     = *reinterpret_cast<const uint4*>(&qt[d * 72 + s0]);
        *reinterpret_cast<uint4*>(qp + 8) = *reinterpret_cast<const uint4*>(&qt[d * 72 + s0 + 8]);
        u16* kp = Kws + ((size_t)bh * SEQL + s_base + d) * 64 + s0;
        *reinterpret_cast<uint4*>(kp)     = *reinterpret_cast<const uint4*>(&kt[d * 72 + s0]);
        *reinterpret_cast<uint4*>(kp + 8) = *reinterpret_cast<const uint4*>(&kt[d * 72 + s0 + 8]);
        u16* vp = Vtws + ((size_t)bh * 64 + d) * SEQL + s_base + s0;
        *reinterpret_cast<uint4*>(vp)     = *reinterpret_cast<const uint4*>(&vt[d * 72 + s0]);
        *reinterpret_cast<uint4*>(vp + 8) = *reinterpret_cast<const uint4*>(&vt[d * 72 + s0 + 8]);
    }
}

// ---------------------------------------------------------------------------
// Kernel 2: flash attention, 32x32 MFMA + in-register P (R11, best known).
// One block = 128 q-rows of one (b,h); 4 waves x 32 q-rows.  Each lane owns
// q = q0 + (l&31).  S^T = K*Q^T via mfma_32x32x16; softmax in-lane (+1
// cross-half shfl); P packed to bf16 and redistributed with
// v_permlane32_swap_b32 — no P LDS round-trip.  K/V double-buffered via
// swizzled global_load_lds; T15 lag: PV(t-1) right after QK(t); T13.
// ---------------------------------------------------------------------------
__global__ __launch_bounds__(256, 2) void attn_kernel(
    const u16* __restrict__ Qws, const u16* __restrict__ Kws,
    const u16* __restrict__ Vtws, float* __restrict__ out)
{
    // XCD-chunk swizzle: 512 blocks -> 64 consecutive logical blocks per XCD.
    const int p     = blockIdx.x;
    const int lid   = (p & 7) * 64 + (p >> 3);
    const int qtile = lid & 15;
    const int bh    = lid >> 4;
    const int b     = bh >> 4;
    const int h     = bh & 15;

    const int tid = threadIdx.x;
    const int w   = tid >> 6;
    const int l   = tid & 63;
    const int lq  = l & 31;                   // lane's q-row
    const int hi  = l >> 5;                   // lane half
    const int q0  = qtile * 128 + w * 32;

    __shared__ u16 k_lds[2][64 * 64];         // [buf][key_local][dh], swizzled
    __shared__ u16 v_lds[2][64 * 64];         // [buf][d][key_local], swizzled

    const u16* Kb = Kws  + (size_t)bh * SEQL * 64;
    const u16* Vb = Vtws + (size_t)bh * 64 * SEQL;

    const int rs8 = l >> 3;                   // 0..7
    const int sx  = (l & 7) ^ rs8;            // inverse-swizzled source slot

    #define STAGE(bb, k0)                                                     \
    {   _Pragma("unroll")                                                     \
        for (int a = 0; a < 2; ++a) {                                         \
            const int rbase = w * 16 + a * 8;                                 \
            const int r     = rbase + rs8;                                    \
            gload_lds16(Kb + (size_t)((k0) + r) * 64 + sx * 8,                \
                        &k_lds[bb][rbase * 64]);                              \
            gload_lds16(Vb + (size_t)r * SEQL + (k0) + sx * 8,                \
                        &v_lds[bb][rbase * 64]);                              \
        }                                                                     \
    }

    // Q fragments (B of S^T): Q[q0+lq][s*16 + hi*8 ..+8]
    bf16x8 qf[4];
    #pragma unroll
    for (int s = 0; s < 4; ++s)
        qf[s] = *reinterpret_cast<const bf16x8*>(
            Qws + ((size_t)bh * SEQL + q0 + lq) * 64 + s * 16 + hi * 8);

    f32x16 zero16;
    #pragma unroll
    for (int j = 0; j < 16; ++j) zero16[j] = 0.f;

    f32x16 acc[2];                            // O^T accum, d-tiles 0/1
    acc[0] = zero16; acc[1] = zero16;
    float mrow = -1e30f;
    float lrow = 0.f;

    // swizzled 16B slot offsets (bytes) within a 128B LDS row; row&7 == lq&7
    int koff[4];
    #pragma unroll
    for (int s = 0; s < 4; ++s) koff[s] = ((s * 2 + hi) ^ (lq & 7)) * 16;

    // A/B named prev-state (registers live across the barrier)
    bf16x8 vfA[2][4], vfB[2][4];
    bf16x8 pfA[4], pfB[4];

    STAGE(0, 0);
    __syncthreads();

    auto body = [&](bf16x8 (&vfC)[2][4], bf16x8 (&pfC)[4],
                    bf16x8 (&vfP)[2][4], bf16x8 (&pfP)[4],
                    int t, bool has_prev) {
        const int cur = t & 1;
        if (t + 1 < SEQL / 64) STAGE(cur ^ 1, (t + 1) * 64);

        // ---- K fragments (A of S^T): row = kt*32+lq, dh-slice s
        const char* kb = reinterpret_cast<const char*>(&k_lds[cur][0]);
        bf16x8 kf0[4], kf1[4];
        #pragma unroll
        for (int s = 0; s < 4; ++s) {
            kf0[s] = *reinterpret_cast<const bf16x8*>(kb + lq * 128 + koff[s]);
            kf1[s] = *reinterpret_cast<const bf16x8*>(kb + (32 + lq) * 128 + koff[s]);
        }

        __builtin_amdgcn_s_setprio(1);
        f32x16 st0 = __builtin_amdgcn_mfma_f32_32x32x16_bf16(kf0[0], qf[0], zero16, 0, 0, 0);
        f32x16 st1 = __builtin_amdgcn_mfma_f32_32x32x16_bf16(kf1[0], qf[0], zero16, 0, 0, 0);
        #pragma unroll
        for (int s = 1; s < 4; ++s) {
            st0 = __builtin_amdgcn_mfma_f32_32x32x16_bf16(kf0[s], qf[s], st0, 0, 0, 0);
            st1 = __builtin_amdgcn_mfma_f32_32x32x16_bf16(kf1[s], qf[s], st1, 0, 0, 0);
        }
        // ---- PV(t-1) from registers (overlaps the softmax below)
        if (has_prev) {
            #pragma unroll
            for (int s = 0; s < 4; ++s) {
                acc[0] = __builtin_amdgcn_mfma_f32_32x32x16_bf16(vfP[0][s], pfP[s], acc[0], 0, 0, 0);
                acc[1] = __builtin_amdgcn_mfma_f32_32x32x16_bf16(vfP[1][s], pfP[s], acc[1], 0, 0, 0);
            }
        }
        __builtin_amdgcn_s_setprio(0);

        // ---- V(t) fragments (A of PV): row d = dt*32+lq, key-slice s
        const char* vb = reinterpret_cast<const char*>(&v_lds[cur][0]);
        #pragma unroll
        for (int dt = 0; dt < 2; ++dt)
            #pragma unroll
            for (int s = 0; s < 4; ++s)
                vfC[dt][s] = *reinterpret_cast<const bf16x8*>(vb + (dt * 32 + lq) * 128 + koff[s]);

        // ---- softmax: in-lane over 32 keys + one cross-half shfl
        float t0 = fmaxf(fmaxf(st0[0], st0[1]),  fmaxf(st0[2], st0[3]));
        float t1 = fmaxf(fmaxf(st0[4], st0[5]),  fmaxf(st0[6], st0[7]));
        float t2 = fmaxf(fmaxf(st0[8], st0[9]),  fmaxf(st0[10], st0[11]));
        float t3 = fmaxf(fmaxf(st0[12], st0[13]), fmaxf(st0[14], st0[15]));
        float t4 = fmaxf(fmaxf(st1[0], st1[1]),  fmaxf(st1[2], st1[3]));
        float t5 = fmaxf(fmaxf(st1[4], st1[5]),  fmaxf(st1[6], st1[7]));
        float t6 = fmaxf(fmaxf(st1[8], st1[9]),  fmaxf(st1[10], st1[11]));
        float t7 = fmaxf(fmaxf(st1[12], st1[13]), fmaxf(st1[14], st1[15]));
        float mx = fmaxf(fmaxf(fmaxf(t0, t1), fmaxf(t2, t3)),
                         fmaxf(fmaxf(t4, t5), fmaxf(t6, t7)));
        mx = fmaxf(mx, __shfl_xor(mx, 32, 64));

        // defer-rescale (T13); acc already holds PV(t-1)
        if (!__all(mx <= mrow + 8.f)) {
            const float mn    = fmaxf(mrow, mx);
            const float alpha = __builtin_amdgcn_exp2f(mrow - mn);
            mrow = mn;
            lrow *= alpha;
            #pragma unroll
            for (int j = 0; j < 16; ++j) { acc[0][j] *= alpha; acc[1][j] *= alpha; }
        }

        // ---- exp2 + pack + permlane redistribution (P stays in registers)
        float rs0 = 0.f, rs1 = 0.f;
        u32 wd[16];
        {
            float pp[16];
            #pragma unroll
            for (int r = 0; r < 16; ++r) {
                pp[r] = __builtin_amdgcn_exp2f(st0[r] - mrow);
                if (r & 1) rs1 += pp[r]; else rs0 += pp[r];
            }
            #pragma unroll
            for (int j = 0; j < 8; ++j) wd[j] = pack2(pp[2 * j], pp[2 * j + 1]);
        }
        {
            float pp[16];
            #pragma unroll
            for (int r = 0; r < 16; ++r) {
                pp[r] = __builtin_amdgcn_exp2f(st1[r] - mrow);
                if (r & 1) rs1 += pp[r]; else rs0 += pp[r];
            }
            #pragma unroll
            for (int j = 0; j < 8; ++j) wd[8 + j] = pack2(pp[2 * j], pp[2 * j + 1]);
        }
        lrow += rs0 + rs1;

        plswap(wd[0],  wd[2]);  plswap(wd[1],  wd[3]);
        plswap(wd[4],  wd[6]);  plswap(wd[5],  wd[7]);
        plswap(wd[8],  wd[10]); plswap(wd[9],  wd[11]);
        plswap(wd[12], wd[14]); plswap(wd[13], wd[15]);

        #pragma unroll
        for (int s = 0; s < 4; ++s) {
            u32x4 tmp = { wd[s * 4 + 0], wd[s * 4 + 1], wd[s * 4 + 2], wd[s * 4 + 3] };
            pfC[s] = __builtin_bit_cast(bf16x8, tmp);
        }

        // ---- barrier: drains vmcnt (stage of t+1) and protects buf[cur]
        __syncthreads();
    };

    for (int tt = 0; tt < SEQL / 64; tt += 2) {
        body(vfA, pfA, vfB, pfB, tt,     tt != 0);
        body(vfB, pfB, vfA, pfA, tt + 1, true);
    }

    // ---- epilogue: final PV(31), combine halves of l, normalize, store
    #pragma unroll
    for (int s = 0; s < 4; ++s) {
        acc[0] = __builtin_amdgcn_mfma_f32_32x32x16_bf16(vfB[0][s], pfB[s], acc[0], 0, 0, 0);
        acc[1] = __builtin_amdgcn_mfma_f32_32x32x16_bf16(vfB[1][s], pfB[s], acc[1], 0, 0, 0);
    }
    const float inv = 1.f / (lrow + __shfl_xor(lrow, 32, 64));

    // O^T[d][q]: d = dt*32 + rg*8 + hi*4 + (r&3), q = q0+lq
    float* op = out + ((size_t)b * SEQL + q0 + lq) * 1024 + h * 64 + hi * 4;
    #pragma unroll
    for (int dt = 0; dt < 2; ++dt)
        #pragma unroll
        for (int rg = 0; rg < 4; ++rg) {
            float4 o;
            o.x = acc[dt][rg * 4 + 0] * inv;
            o.y = acc[dt][rg * 4 + 1] * inv;
            o.z = acc[dt][rg * 4 + 2] * inv;
            o.w = acc[dt][rg * 4 + 3] * inv;
            *reinterpret_cast<float4*>(op + dt * 32 + rg * 8) = o;
        }
}

extern "C" void kernel_launch(void* const* d_in, const int* in_sizes, int n_in,
                              void* d_out, int out_size, void* d_ws, size_t ws_size,
                              hipStream_t stream) {
    const float* x  = (const float*)d_in[0];
    const float* Wq = (const float*)d_in[1];
    const float* bq = (const float*)d_in[2];
    const float* Wk = (const float*)d_in[3];
    const float* bk = (const float*)d_in[4];
    const float* Wv = (const float*)d_in[5];
    const float* bv = (const float*)d_in[6];
    float* out = (float*)d_out;

    const size_t per = (size_t)BHN * SEQL * 64;   // 4Mi elems per matrix
    u16* Qws = (u16*)d_ws;
    u16* Kws = Qws + per;
    u16* Vt  = Kws + per;
    u16* Wb  = Vt  + per;                         // 3*65536 bf16 = 384 KB

    wconv_kernel<<<dim3(64, 3), 256, 0, stream>>>(Wq, Wk, Wv, Wb);
    qkv_kernel<<<dim3(64, 16), 256, 0, stream>>>(x, Wb, bq, bk, bv, Qws, Kws, Vt);
    attn_kernel<<<dim3(512), 256, 0, stream>>>(Qws, Kws, Vt, out);
}